// Round 5
// baseline (220.596 us; speedup 1.0000x reference)
//
#include <hip/hip_runtime.h>
#include <hip/hip_fp16.h>

// ---------------------------------------------------------------------------
// 3-layer GCN, CSR-gather, fp16 dataflow + MFMA GEMM, fused pipeline R22:
// R21 (211.6us) + DEGREE-SORTED processing order for gather_gemv/gather3.
//   memset:       cnt8 = 0
//   count+wcast:  8-BANK cnt histogram (XCD-local atomics) || Wt cast
//                 || histo zero
//   scan_blk:     deg, dis, block scan; 64-bin degree histogram
//   scan_add:     row_ptr + per-bank base8; block0 scans histo -> binCursor
//   gemm1+bin+perm: HWS1 = half(dis*(x@W1)) || CSR bin || counting-sort
//                 scatter -> perm (nodes grouped by degree)
//   gather+gemm2: h1 = relu(dis*S HWS1 + b1) -> LDS -> HWS2 (node set fixed
//                 by GEMM tile; queue-balanced, depth-4)
//   gather+gemv:  nodes processed in perm order -> equal-degree waves
//   gather3:      nodes processed in perm order -> equal-degree lanes
// Divergent-loop arithmetic: wave time = MAX trip count over lanes. Poisson
// deg: E[max of 64] ~ 2x mean (gather3), E[max of 4 quarters] ~ 1.4x
// (gemv). Degree grouping makes waves uniform. Processing order is free:
// each work item writes only its own node's output.
// Lessons: R18 row-sort FAILED; R19 dis[s]-loads FAILED; R20 depth-8 FAILED
// (occupancy trade); R19/R21 banked count neutral-to-positive. VGPR<64 hot.
// ---------------------------------------------------------------------------

typedef _Float16 v8h __attribute__((ext_vector_type(8)));
typedef float v4f __attribute__((ext_vector_type(4)));

// fused: 8-bank edge count + rank record (blocks [0,BE)) + weight cast +
// degree-histogram zero (first wcast block).
__global__ __launch_bounds__(256) void k_count_wcast(const int* __restrict__ dst,
                                                     int* __restrict__ cnt8,
                                                     int* __restrict__ rank, int nE,
                                                     int BE, int nN,
                                                     const float* __restrict__ W1,
                                                     const float* __restrict__ W2,
                                                     __half* __restrict__ Wt1,
                                                     __half* __restrict__ Wt2,
                                                     int* __restrict__ histo) {
    int b = blockIdx.x;
    if (b < BE) {
        int e = b * 256 + threadIdx.x;
        if (e < nE) {
            int bank = b & 7;
            rank[e] = atomicAdd(&cnt8[bank * nN + dst[e]], 1);
        }
    } else {
        if (b == BE && threadIdx.x < 64) histo[threadIdx.x] = 0;
        int i = (b - BE) * 256 + threadIdx.x;   // 0..16383
        int k = i >> 7, c = i & 127;
        Wt1[c * 128 + k] = __float2half(W1[i]);
        Wt2[c * 128 + k] = __float2half(W2[i]);
    }
}

// scan stage 1: deg = sum of 8 banks, dis = rsqrt(deg+1), deg out,
// 64-bin degree histogram (LDS-local then one atomic per bin per block).
__global__ __launch_bounds__(256) void k_scan_blk(const int* __restrict__ cnt8,
                                                  float* __restrict__ dis,
                                                  int* __restrict__ deg,
                                                  int* __restrict__ excl,
                                                  int* __restrict__ blk_sum,
                                                  int* __restrict__ histo, int nN) {
    __shared__ int sm[256];
    __shared__ int lh[64];
    const int t = threadIdx.x;
    if (t < 64) lh[t] = 0;
    int i = blockIdx.x * 256 + t;
    int v = 0;
    if (i < nN) {
#pragma unroll
        for (int b = 0; b < 8; ++b) v += cnt8[b * nN + i];
        dis[i] = rsqrtf((float)v + 1.0f);
        deg[i] = v;
    }
    sm[t] = v;
    __syncthreads();
    if (i < nN) atomicAdd(&lh[v < 63 ? v : 63], 1);
#pragma unroll
    for (int off = 1; off < 256; off <<= 1) {
        int x = (t >= off) ? sm[t - off] : 0;
        __syncthreads();
        sm[t] += x;
        __syncthreads();
    }
    if (i < nN) excl[i] = sm[t] - v;
    if (t == 255) blk_sum[blockIdx.x] = sm[255];
    __syncthreads();
    if (t < 64 && lh[t]) atomicAdd(&histo[t], lh[t]);
}

// stage 2+3 fused + per-bank base8 + binCursor (exclusive scan of histo).
__global__ __launch_bounds__(256) void k_scan_add(const int* __restrict__ excl,
                                                  const int* __restrict__ blk_sum,
                                                  const int* __restrict__ cnt8,
                                                  int* __restrict__ row_ptr,
                                                  int* __restrict__ base8,
                                                  const int* __restrict__ histo,
                                                  int* __restrict__ binCursor,
                                                  int nN, int nB) {
    __shared__ int sm[256];
    const int t = threadIdx.x;
    int v = (t < nB) ? blk_sum[t] : 0;
    sm[t] = v;
    __syncthreads();
#pragma unroll
    for (int off = 1; off < 256; off <<= 1) {
        int x = (t >= off) ? sm[t - off] : 0;
        __syncthreads();
        sm[t] += x;
        __syncthreads();
    }
    int i = blockIdx.x * 256 + t;
    if (i < nN) {
        int b = i >> 8;
        int rp = excl[i] + sm[b] - blk_sum[b];
        row_ptr[i] = rp;
        int off = rp;
#pragma unroll
        for (int bk = 0; bk < 8; ++bk) {
            base8[i * 8 + bk] = off;
            off += cnt8[bk * nN + i];
        }
    }
    if (i == 0) row_ptr[nN] = sm[255];
    if (blockIdx.x == 0 && t == 0) {
        int s = 0;
#pragma unroll
        for (int k = 0; k < 64; ++k) { binCursor[k] = s; s += histo[k]; }
    }
}

// add 8 halves (packed in a float4) into acc[8] (fp32)
__device__ __forceinline__ void add8(float acc[8], float4 r) {
    __half2* hp = (__half2*)&r;
#pragma unroll
    for (int k = 0; k < 4; ++k) {
        float2 f = __half22float2(hp[k]);
        acc[2 * k] += f.x;
        acc[2 * k + 1] += f.y;
    }
}

// QUARTER-WAVE gather: 16 lanes per node row, 16B (8 halves) per lane.
__device__ __forceinline__ void gather_row16(const float4* __restrict__ Hv,
                                             const int* __restrict__ row_ptr,
                                             const int* __restrict__ src_csr,
                                             int g, int f8, float acc[8]) {
    int beg = row_ptr[g], end = row_ptr[g + 1];
#pragma unroll
    for (int k = 0; k < 8; ++k) acc[k] = 0.f;
    add8(acc, Hv[(size_t)g * 16 + f8]);   // self term
    int e = beg;
    for (; e + 4 <= end; e += 4) {        // 4-deep batch: r[4]x4 = 16 VGPRs
        int s[4];
#pragma unroll
        for (int j = 0; j < 4; ++j) s[j] = src_csr[e + j];
        float4 r[4];
#pragma unroll
        for (int j = 0; j < 4; ++j) r[j] = Hv[(size_t)s[j] * 16 + f8];
#pragma unroll
        for (int j = 0; j < 4; ++j) add8(acc, r[j]);
    }
    for (; e < end; ++e) add8(acc, Hv[(size_t)src_csr[e] * 16 + f8]);
}

// FUSED dispatch: blocks [0,BG) = layer-1 MFMA GEMM; [BG,BG+BE) = CSR bin;
// [BG+BE,BG+BE+BN) = counting-sort scatter -> perm (degree-grouped order).
__global__ __launch_bounds__(256) void k_gemm_bin(const float* __restrict__ X32,
                                                  const __half* __restrict__ Wt,
                                                  const float* __restrict__ dis,
                                                  __half* __restrict__ HWS,
                                                  int nrows, int BG,
                                                  const int* __restrict__ src,
                                                  const int* __restrict__ dst,
                                                  const int* __restrict__ rank,
                                                  const int* __restrict__ base8,
                                                  int* __restrict__ src_csr, int nE,
                                                  int BE,
                                                  const int* __restrict__ deg,
                                                  int* __restrict__ binCursor,
                                                  int* __restrict__ perm, int nN) {
    __shared__ __half xs[64 * 136];
    if (blockIdx.x >= BG + BE) {
        // --- perm scatter: block-local counting sort by degree bin ---
        int* sh = (int*)xs;              // [0:64) lhist, [64:128) lbase, [128:192) lcnt
        int i = (blockIdx.x - BG - BE) * 256 + threadIdx.x;
        if (threadIdx.x < 64) { sh[threadIdx.x] = 0; sh[128 + threadIdx.x] = 0; }
        __syncthreads();
        int bin = 0;
        if (i < nN) {
            int d = deg[i];
            bin = d < 63 ? d : 63;
            atomicAdd(&sh[bin], 1);
        }
        __syncthreads();
        if (threadIdx.x < 64 && sh[threadIdx.x])
            sh[64 + threadIdx.x] = atomicAdd(&binCursor[threadIdx.x], sh[threadIdx.x]);
        __syncthreads();
        if (i < nN) {
            int r = atomicAdd(&sh[128 + bin], 1);
            perm[sh[64 + bin] + r] = i;
        }
        return;
    }
    if (blockIdx.x >= BG) {
        // --- binning path (no atomics) ---
        int eb = blockIdx.x - BG;
        int e = eb * 256 + threadIdx.x;
        if (e < nE) {
            int d = dst[e];
            int bank = eb & 7;
            src_csr[base8[d * 8 + bank] + rank[e]] = src[e];
        }
        return;
    }

    // --- GEMM path ---
    const int t = threadIdx.x;
    const int row0 = blockIdx.x * 64;

#pragma unroll
    for (int i = 0; i < 8; ++i) {
        int f = t + i * 256;
        int r = f >> 5, k4 = f & 31;
        int gr = row0 + r;
        float4 v = make_float4(0.f, 0.f, 0.f, 0.f);
        if (gr < nrows) v = ((const float4*)X32)[(size_t)gr * 32 + k4];
        __half2 h01 = __float22half2_rn(make_float2(v.x, v.y));
        __half2 h23 = __float22half2_rn(make_float2(v.z, v.w));
        float2 packed;
        *(__half2*)&packed.x = h01;
        *(__half2*)&packed.y = h23;
        *(float2*)&xs[r * 136 + k4 * 4] = packed;
    }
    __syncthreads();

    const int w = t >> 6;
    const int l = t & 63;
    const int mrow = l & 15;
    const int kq = l >> 4;

    v8h a[4];
#pragma unroll
    for (int kk = 0; kk < 4; ++kk)
        a[kk] = *(const v8h*)&xs[(w * 16 + mrow) * 136 + kk * 32 + kq * 8];

    v4f acc[8];
#pragma unroll
    for (int c = 0; c < 8; ++c) acc[c] = (v4f){0.f, 0.f, 0.f, 0.f};

#pragma unroll
    for (int kk = 0; kk < 4; ++kk) {
#pragma unroll
        for (int c = 0; c < 8; ++c) {
            v8h b = *(const v8h*)&Wt[(size_t)(c * 16 + mrow) * 128 + kk * 32 + kq * 8];
            acc[c] = __builtin_amdgcn_mfma_f32_16x16x32_f16(a[kk], b, acc[c], 0, 0, 0);
        }
    }

    float dn[4];
#pragma unroll
    for (int r = 0; r < 4; ++r) {
        int grow = row0 + w * 16 + kq * 4 + r;
        dn[r] = (grow < nrows) ? dis[grow] : 0.f;
    }
#pragma unroll
    for (int c = 0; c < 8; ++c) {
#pragma unroll
        for (int r = 0; r < 4; ++r) {
            int grow = row0 + w * 16 + kq * 4 + r;
            if (grow < nrows)
                HWS[(size_t)grow * 128 + c * 16 + mrow] =
                    __float2half(acc[c][r] * dn[r]);
        }
    }
}

// FUSED layer-1 gather + layer-2 GEMM, 512 threads. (Node set fixed by GEMM
// tile -> no perm here; LDS queue balances within the block.)
__global__ __launch_bounds__(512) void k_gather_gemm(const __half* __restrict__ HWS1,
                                                     const int* __restrict__ row_ptr,
                                                     const int* __restrict__ src_csr,
                                                     const float* __restrict__ dis,
                                                     const float* __restrict__ bias,
                                                     const __half* __restrict__ Wt,
                                                     __half* __restrict__ HWS2,
                                                     int nN) {
    __shared__ __half xs[64 * 136];
    __shared__ int q;
    const int t = threadIdx.x;
    const int row0 = blockIdx.x * 64;
    const int l = t & 63;
    const int f8 = t & 15;            // lane within quarter-wave
    const int qbase = l & 48;         // base lane of this quarter in the wave
    const float4* Hv = (const float4*)HWS1;

    float bv[8];
    *(float4*)&bv[0] = ((const float4*)bias)[f8 * 2];
    *(float4*)&bv[4] = ((const float4*)bias)[f8 * 2 + 1];

    if (t == 0) q = 0;
    __syncthreads();

    for (;;) {
        int lr = 0;
        if (f8 == 0) lr = atomicAdd(&q, 1);
        lr = __shfl(lr, qbase, 64);
        if (lr >= 64) break;
        int g = row0 + lr;
        float acc[8];
        __half2 h[4];
        if (g < nN) {
            gather_row16(Hv, row_ptr, src_csr, g, f8, acc);
            float dn = dis[g];
#pragma unroll
            for (int k = 0; k < 4; ++k)
                h[k] = __float22half2_rn(make_float2(
                    fmaxf(acc[2 * k] * dn + bv[2 * k], 0.f),
                    fmaxf(acc[2 * k + 1] * dn + bv[2 * k + 1], 0.f)));
        } else {
#pragma unroll
            for (int k = 0; k < 4; ++k) h[k] = __float2half2_rn(0.f);
        }
        *(float4*)&xs[lr * 136 + f8 * 8] = *(float4*)h;   // 16B ds_write_b128
    }
    __syncthreads();

    const int w = t >> 6;        // wave 0..7
    const int mrow = l & 15;
    const int kq = l >> 4;
    const int rgrp = (w & 3) * 16;   // row group
    const int cgrp = (w >> 2) * 4;   // col-tile group (4 tiles of 16)

    v8h a[4];
#pragma unroll
    for (int kk = 0; kk < 4; ++kk)
        a[kk] = *(const v8h*)&xs[(rgrp + mrow) * 136 + kk * 32 + kq * 8];

    v4f acc[4];
#pragma unroll
    for (int c = 0; c < 4; ++c) acc[c] = (v4f){0.f, 0.f, 0.f, 0.f};

#pragma unroll
    for (int kk = 0; kk < 4; ++kk) {
#pragma unroll
        for (int c = 0; c < 4; ++c) {
            v8h b = *(const v8h*)&Wt[(size_t)((cgrp + c) * 16 + mrow) * 128 + kk * 32 + kq * 8];
            acc[c] = __builtin_amdgcn_mfma_f32_16x16x32_f16(a[kk], b, acc[c], 0, 0, 0);
        }
    }

    float dn4[4];
#pragma unroll
    for (int r = 0; r < 4; ++r) {
        int grow = row0 + rgrp + kq * 4 + r;
        dn4[r] = (grow < nN) ? dis[grow] : 0.f;
    }
#pragma unroll
    for (int c = 0; c < 4; ++c) {
#pragma unroll
        for (int r = 0; r < 4; ++r) {
            int grow = row0 + rgrp + kq * 4 + r;
            if (grow < nN)
                HWS2[(size_t)grow * 128 + (cgrp + c) * 16 + mrow] =
                    __float2half(acc[c][r] * dn4[r]);
        }
    }
}

// FUSED layer-2 gather + layer-3 gemv, DEGREE-SORTED: the 16 nodes of a
// block come from perm -> the 4 quarter-waves of each wave have near-equal
// degrees -> divergent edge loops run near-uniform trip counts.
__global__ __launch_bounds__(256) void k_gather_gemv(const __half* __restrict__ HWS2,
                                                     const int* __restrict__ row_ptr,
                                                     const int* __restrict__ src_csr,
                                                     const float* __restrict__ dis,
                                                     const float* __restrict__ bias,
                                                     const float* __restrict__ W3,
                                                     const int* __restrict__ perm,
                                                     float* __restrict__ hw3s, int nN) {
    int gi = blockIdx.x * 16 + (threadIdx.x >> 4);
    if (gi >= nN) return;
    int g = perm[gi];
    int f8 = threadIdx.x & 15;
    float acc[8];
    gather_row16((const float4*)HWS2, row_ptr, src_csr, g, f8, acc);
    float dn = dis[g];
    float bv[8], w3[8];
    *(float4*)&bv[0] = ((const float4*)bias)[f8 * 2];
    *(float4*)&bv[4] = ((const float4*)bias)[f8 * 2 + 1];
    *(float4*)&w3[0] = ((const float4*)W3)[f8 * 2];
    *(float4*)&w3[4] = ((const float4*)W3)[f8 * 2 + 1];
    float sum = 0.f;
#pragma unroll
    for (int k = 0; k < 8; ++k)
        sum += fmaxf(acc[k] * dn + bv[k], 0.f) * w3[k];
#pragma unroll
    for (int off = 8; off > 0; off >>= 1) sum += __shfl_down(sum, off, 16);
    if (f8 == 0) hw3s[g] = sum * dn;
}

// scalar pull-aggregation + final relu, DEGREE-SORTED: lanes of a wave get
// 64 consecutive perm entries -> near-equal degrees -> no max-of-64 waste.
__global__ __launch_bounds__(256) void k_gather3(const float* __restrict__ hw3s,
                                                 const int* __restrict__ row_ptr,
                                                 const int* __restrict__ src_csr,
                                                 const float* __restrict__ dis,
                                                 const float* __restrict__ b3,
                                                 const int* __restrict__ perm,
                                                 float* __restrict__ out, int nN) {
    int i0 = blockIdx.x * 256 + threadIdx.x;
    if (i0 >= nN) return;
    int i = perm[i0];
    float acc = hw3s[i];
    int beg = row_ptr[i], end = row_ptr[i + 1];
    for (int e = beg; e < end; ++e) acc += hw3s[src_csr[e]];
    out[i] = fmaxf(acc * dis[i] + b3[0], 0.f);
}

extern "C" void kernel_launch(void* const* d_in, const int* in_sizes, int n_in,
                              void* d_out, int out_size, void* d_ws, size_t ws_size,
                              hipStream_t stream) {
    const float* x  = (const float*)d_in[0];
    const int*   ei = (const int*)d_in[1];
    const float* W1 = (const float*)d_in[2];
    const float* b1 = (const float*)d_in[3];
    const float* W2 = (const float*)d_in[4];
    const float* b2 = (const float*)d_in[5];
    const float* W3 = (const float*)d_in[6];
    const float* b3 = (const float*)d_in[7];

    const int nN = in_sizes[0] / 128;
    const int nE = in_sizes[1] / 2;
    const int* src = ei;
    const int* dst = ei + nE;

    const int nB = (nN + 255) / 256;   // scan blocks (<=256)

    // workspace layout
    char* p = (char*)d_ws;
    int*    cnt8     = (int*)p;           p += (size_t)nN * 8 * 4;
    int*    base8    = (int*)p;           p += (size_t)nN * 8 * 4;
    int*    excl     = (int*)p;           p += (size_t)nN * 4;
    int*    blk_sum  = (int*)p;           p += (size_t)(nB + 1) * 4;
    int*    row_ptr  = (int*)p;           p += (size_t)(nN + 1) * 4;
    int*    rank     = (int*)p;           p += (size_t)nE * 4;
    int*    src_csr  = (int*)p;           p += (size_t)nE * 4;
    float*  dis      = (float*)p;         p += (size_t)nN * 4;
    float*  hw3s     = (float*)p;         p += (size_t)nN * 4;
    int*    deg      = (int*)p;           p += (size_t)nN * 4;
    int*    perm     = (int*)p;           p += (size_t)nN * 4;
    int*    histo    = (int*)p;           p += 64 * 4;
    int*    binCur   = (int*)p;           p += 64 * 4;
    p = (char*)(((uintptr_t)p + 255) & ~(uintptr_t)255);
    __half* Wt1      = (__half*)p;        p += (size_t)128 * 128 * 2;
    __half* Wt2      = (__half*)p;        p += (size_t)128 * 128 * 2;
    __half* bufA     = (__half*)p;        p += (size_t)nN * 128 * 2;  // HWS1
    p = (char*)(((uintptr_t)p + 255) & ~(uintptr_t)255);
    __half* bufB     = (__half*)p;        p += (size_t)nN * 128 * 2;  // HWS2

    const int BE  = (nE + 255) / 256;            // 2344
    const int BN  = (nN + 255) / 256;            // 196
    const int BG  = (nN + 63) / 64;              // 782
    const int BGV = (nN + 15) / 16;              // 3125

    // --- CSR build + norms + weight cast (banked count) ---
    hipMemsetAsync(cnt8, 0, (size_t)nN * 8 * sizeof(int), stream);
    k_count_wcast<<<BE + 64, 256, 0, stream>>>(dst, cnt8, rank, nE, BE, nN,
                                               W1, W2, Wt1, Wt2, histo);
    k_scan_blk<<<nB, 256, 0, stream>>>(cnt8, dis, deg, excl, blk_sum, histo, nN);
    k_scan_add<<<nB, 256, 0, stream>>>(excl, blk_sum, cnt8, row_ptr, base8,
                                       histo, binCur, nN, nB);

    // --- layer-1 GEMM || atomic-free binning || degree-sort scatter ---
    k_gemm_bin<<<BG + BE + BN, 256, 0, stream>>>(x, Wt1, dis, bufA, nN, BG,
                                                 src, dst, rank, base8, src_csr,
                                                 nE, BE, deg, binCur, perm, nN);

    // --- fused layer-1 gather + layer-2 GEMM: HWS1 -> HWS2 (512 thr) ---
    k_gather_gemm<<<BG, 512, 0, stream>>>(bufA, row_ptr, src_csr, dis, b1, Wt2,
                                          bufB, nN);

    // --- fused layer-2 gather + layer-3 gemv (degree-sorted) ---
    k_gather_gemv<<<BGV, 256, 0, stream>>>(bufB, row_ptr, src_csr, dis, b2, W3,
                                           perm, hw3s, nN);

    // --- layer-3 scalar gather (degree-sorted) -> d_out ---
    k_gather3<<<BN, 256, 0, stream>>>(hw3s, row_ptr, src_csr, dis, b3, perm,
                                      (float*)d_out, nN);
}